// Round 12
// baseline (553.951 us; speedup 1.0000x reference)
//
#include <hip/hip_runtime.h>
#include <hip/hip_fp16.h>

#define FDIM 128
#define NGRAPH 256
#define NCLS 10
#define AGG_NODES 8     // nodes per block in k_agg_squash (512 threads = 8 waves)
#define STATS_BLOCKS 256
#define CSTRIDE 16      // ints per counter slot (one 64B line) — kills per-line atomic serialization
#define ELLCAP 64       // slots per node; max degree (Poisson mean 12.8) is far below this

__device__ __forceinline__ unsigned encf(float f) {
  unsigned b = __float_as_uint(f);
  return (b & 0x80000000u) ? ~b : (b | 0x80000000u);
}
__device__ __forceinline__ float decf(unsigned u) {
  if (u == 0u) return 0.f;  // empty segment -> 0 (matches isfinite->0)
  return (u & 0x80000000u) ? __uint_as_float(u & 0x7FFFFFFFu) : __uint_as_float(~u);
}

// ---------- BN partial sums (blocks 0..255) + batch bounds + W1/W2 -> fp16 ----------
__global__ __launch_bounds__(256) void k_bn(const float* __restrict__ x,
                                            float* __restrict__ partS,
                                            float* __restrict__ partQ, int total4,
                                            const int* __restrict__ batch,
                                            int* __restrict__ gstart,
                                            int* __restrict__ gend,
                                            const float* __restrict__ gcn_w,
                                            __half* __restrict__ W16,
                                            int nbN, int N) {
  int t = threadIdx.x;
  if (blockIdx.x >= STATS_BLOCKS + nbN) {
    // convert W layers 1,2 to fp16: 2*128*128 = 32768 elems, 128 blocks
    int idx = (blockIdx.x - STATS_BLOCKS - nbN) * 256 + t;
    if (idx < 2 * FDIM * FDIM) W16[idx] = __float2half(gcn_w[FDIM * FDIM + idx]);
    return;
  }
  if (blockIdx.x >= STATS_BLOCKS) {
    int e = (blockIdx.x - STATS_BLOCKS) * 256 + t;
    if (e < N) {
      int b = batch[e];
      if (e == 0 || batch[e - 1] != b) gstart[b] = e;
      if (e == N - 1) gend[b] = N;
      else if (batch[e + 1] != b) gend[b] = e + 1;
    }
    return;
  }
  __shared__ float ss[1024];
  __shared__ float sq[1024];
  float s0 = 0, s1 = 0, s2 = 0, s3 = 0, q0 = 0, q1 = 0, q2 = 0, q3 = 0;
  for (int i = blockIdx.x * 256 + t; i < total4; i += STATS_BLOCKS * 256) {
    float4 v = ((const float4*)x)[i];
    s0 += v.x; q0 += v.x * v.x;
    s1 += v.y; q1 += v.y * v.y;
    s2 += v.z; q2 += v.z * v.z;
    s3 += v.w; q3 += v.w * v.w;
  }
  int fb = (t & 31) * 4, slot = t >> 5;
  ss[slot * 128 + fb + 0] = s0; ss[slot * 128 + fb + 1] = s1;
  ss[slot * 128 + fb + 2] = s2; ss[slot * 128 + fb + 3] = s3;
  sq[slot * 128 + fb + 0] = q0; sq[slot * 128 + fb + 1] = q1;
  sq[slot * 128 + fb + 2] = q2; sq[slot * 128 + fb + 3] = q3;
  __syncthreads();
  if (t < 128) {
    float a = 0, b = 0;
    for (int s = 0; s < 8; s++) { a += ss[s * 128 + t]; b += sq[s * 128 + t]; }
    partS[blockIdx.x * 128 + t] = a;
    partQ[blockIdx.x * 128 + t] = b;
  }
}

// ---------- tiny: reduce BN partials -> affine; counts from bounds ----------
__global__ __launch_bounds__(256) void k_aff(const float* __restrict__ partS,
                                             const float* __restrict__ partQ,
                                             const float* __restrict__ gamma,
                                             const float* __restrict__ beta,
                                             float* __restrict__ aff_a,
                                             float* __restrict__ aff_b,
                                             const int* __restrict__ gstart,
                                             const int* __restrict__ gend,
                                             float* __restrict__ countsf, int N) {
  int t = threadIdx.x;
  if (t < NGRAPH) countsf[t] = fmaxf((float)(gend[t] - gstart[t]), 1.0f);
  if (t < FDIM) {
    float a = 0.f, b = 0.f;
    for (int bk = 0; bk < STATS_BLOCKS; bk++) {
      a += partS[bk * 128 + t];
      b += partQ[bk * 128 + t];
    }
    float invN = 1.0f / (float)N;
    float mu = a * invN;
    float var = b * invN - mu * mu;
    float inv = rsqrtf(var + 1e-5f);
    float ga = gamma[t] * inv;
    aff_a[t] = ga;
    aff_b[t] = beta[t] - mu * ga;
  }
}

// ---------- MEGA: gemm0 Hraw=(aff*x)@W (blocks < gemmBlocks, K-tiled 16KB LDS)
// ----------       + ELL edge ingest (remaining blocks) — the two overlap ----------
__global__ __launch_bounds__(256) void k_mega(const float* __restrict__ x,
                                              const float* __restrict__ aff_a,
                                              const float* __restrict__ aff_b,
                                              const float* __restrict__ W,
                                              __half* __restrict__ Hout, int gemmBlocks,
                                              const int* __restrict__ src,
                                              const int* __restrict__ dst,
                                              int* __restrict__ cursor,
                                              int* __restrict__ ell_src, int E, int N) {
  int t = threadIdx.x;
  if (blockIdx.x >= gemmBlocks) {
    int e = (blockIdx.x - gemmBlocks) * 256 + t;
    if (e < E) {
      int s = src[e], d = dst[e];
      if (s != d) {
        int p = atomicAdd(cursor + (size_t)d * CSTRIDE, 1);
        if (p < ELLCAP) ell_src[(size_t)d * ELLCAP + p] = s;
      }
    }
    return;  // edge blocks never reach the barriers below
  }
  __shared__ float sW[32 * 128];   // 16 KB K-tile of W
  __shared__ float sA[128];
  __shared__ float sB[128];
  if (t < 128) { sA[t] = aff_a[t]; sB[t] = aff_b[t]; }
  int tx = t & 31, ty = t >> 5;
  int nodeBase = blockIdx.x * 64 + ty * 8;
  int nidx[8];
#pragma unroll
  for (int i = 0; i < 8; i++) nidx[i] = min(nodeBase + i, N - 1);
  float acc[8][4];
#pragma unroll
  for (int i = 0; i < 8; i++) { acc[i][0] = acc[i][1] = acc[i][2] = acc[i][3] = 0.f; }
  for (int kk = 0; kk < 128; kk += 32) {
    __syncthreads();
#pragma unroll
    for (int i = 0; i < 4; i++) {
      int idx = t * 4 + i * 1024;
      *(float4*)(sW + idx) = *(const float4*)(W + kk * 128 + idx);
    }
    __syncthreads();
#pragma unroll 2
    for (int k2 = 0; k2 < 32; k2 += 4) {
      int k = kk + k2;
      float4 b0 = *(const float4*)(sW + (k2 + 0) * 128 + tx * 4);
      float4 b1 = *(const float4*)(sW + (k2 + 1) * 128 + tx * 4);
      float4 b2 = *(const float4*)(sW + (k2 + 2) * 128 + tx * 4);
      float4 b3 = *(const float4*)(sW + (k2 + 3) * 128 + tx * 4);
      float4 va = *(const float4*)(sA + k);
      float4 vb = *(const float4*)(sB + k);
#pragma unroll
      for (int i = 0; i < 8; i++) {
        float4 a = *(const float4*)(x + (size_t)nidx[i] * 128 + k);
        a.x = fmaf(a.x, va.x, vb.x);
        a.y = fmaf(a.y, va.y, vb.y);
        a.z = fmaf(a.z, va.z, vb.z);
        a.w = fmaf(a.w, va.w, vb.w);
        acc[i][0] = fmaf(a.w, b3.x, fmaf(a.z, b2.x, fmaf(a.y, b1.x, fmaf(a.x, b0.x, acc[i][0]))));
        acc[i][1] = fmaf(a.w, b3.y, fmaf(a.z, b2.y, fmaf(a.y, b1.y, fmaf(a.x, b0.y, acc[i][1]))));
        acc[i][2] = fmaf(a.w, b3.z, fmaf(a.z, b2.z, fmaf(a.y, b1.z, fmaf(a.x, b0.z, acc[i][2]))));
        acc[i][3] = fmaf(a.w, b3.w, fmaf(a.z, b2.w, fmaf(a.y, b1.w, fmaf(a.x, b0.w, acc[i][3]))));
      }
    }
  }
#pragma unroll
  for (int i = 0; i < 8; i++) {
    int node = nodeBase + i;
    if (node < N) {
      __half2 p0 = __floats2half2_rn(acc[i][0], acc[i][1]);
      __half2 p1 = __floats2half2_rn(acc[i][2], acc[i][3]);
      uint2 st;
      st.x = *(unsigned*)&p0;
      st.y = *(unsigned*)&p1;
      *(uint2*)(Hout + (size_t)node * 128 + tx * 4) = st;
    }
  }
}

// ---------- post: scale H by dinv (from cursor) + write deg/dinv arrays ----------
__global__ __launch_bounds__(256) void k_post(const int* __restrict__ cursor,
                                              int* __restrict__ deg,
                                              float* __restrict__ dinv,
                                              __half2* __restrict__ H,
                                              int nScaleBlocks, int N) {
  int t = threadIdx.x;
  if (blockIdx.x < nScaleBlocks) {
    int wv = t >> 6, l = t & 63;
    int row = blockIdx.x * 4 + wv;
    if (row >= N) return;
    float dv = rsqrtf(1.0f + (float)min(cursor[(size_t)row * CSTRIDE], ELLCAP));
    float2 f = __half22float2(H[(size_t)row * 64 + l]);
    H[(size_t)row * 64 + l] = __floats2half2_rn(f.x * dv, f.y * dv);
  } else {
    int i = (blockIdx.x - nScaleBlocks) * 256 + t;
    if (i < N) {
      int d = min(cursor[(size_t)i * CSTRIDE], ELLCAP);
      deg[i] = d;
      dinv[i] = rsqrtf(1.0f + (float)d);
    }
  }
}

// ---------- fused: ELL aggregate + squash + attention + graph scatter
// ----------        + NEXT-LAYER matvec H_next = (dinv*X) @ W16 (GEMM=1) ----------
// One wave per dst node; lane l owns features 2l,2l+1. ILP-4 padded edge loop.
// Matvec: 64 shfl-broadcast iters; lane loads 2 half2 of W16/iter (L1-hot 32 KB).
template <int GEMM>
__global__ __launch_bounds__(512) void k_agg_squash(const __half2* __restrict__ H,
                                                    __half2* __restrict__ Hnext,
                                                    const __half2* __restrict__ W16,
                                                    const int* __restrict__ deg,
                                                    const int* __restrict__ ell_src,
                                                    const float* __restrict__ bias,
                                                    const float* __restrict__ watt,
                                                    const int* __restrict__ batch,
                                                    const float* __restrict__ dinv,
                                                    float* __restrict__ wsum,
                                                    float* __restrict__ msum,
                                                    unsigned* __restrict__ maxenc, int N) {
  __shared__ float l_ws[128];
  __shared__ float l_ms[128];
  __shared__ unsigned l_mx[128];
  int t = threadIdx.x;
  if (t < 128) { l_ws[t] = 0.f; l_ms[t] = 0.f; l_mx[t] = 0u; }
  __syncthreads();

  int wv = t >> 6, l = t & 63;
  int node = blockIdx.x * AGG_NODES + wv;
  int g0 = batch[blockIdx.x * AGG_NODES];
  bool valid = node < N;
  float2 xv = make_float2(0.f, 0.f);
  float att = 0.f;
  int g = g0;
  if (valid) {
    float2 h0 = __half22float2(H[(size_t)node * 64 + l]);
    float a0x = h0.x, a0y = h0.y;
    float a1x = 0.f, a1y = 0.f, a2x = 0.f, a2y = 0.f, a3x = 0.f, a3y = 0.f;
    size_t base = (size_t)node * ELLCAP;
    int cnt = deg[node];
    for (int j = 0; j < cnt; j += 4) {
      int4 ss = *(const int4*)(ell_src + base + j);   // broadcast 16B
      bool v1 = (j + 1 < cnt), v2 = (j + 2 < cnt), v3 = (j + 3 < cnt);
      int s0 = ss.x;
      int s1 = v1 ? ss.y : 0;
      int s2 = v2 ? ss.z : 0;
      int s3 = v3 ? ss.w : 0;
      float m1 = v1 ? 1.f : 0.f;
      float m2 = v2 ? 1.f : 0.f;
      float m3 = v3 ? 1.f : 0.f;
      float2 r0 = __half22float2(H[(size_t)s0 * 64 + l]);
      float2 r1 = __half22float2(H[(size_t)s1 * 64 + l]);
      float2 r2 = __half22float2(H[(size_t)s2 * 64 + l]);
      float2 r3 = __half22float2(H[(size_t)s3 * 64 + l]);
      a0x += r0.x;               a0y += r0.y;
      a1x = fmaf(m1, r1.x, a1x); a1y = fmaf(m1, r1.y, a1y);
      a2x = fmaf(m2, r2.x, a2x); a2y = fmaf(m2, r2.y, a2y);
      a3x = fmaf(m3, r3.x, a3x); a3y = fmaf(m3, r3.y, a3y);
    }
    float dn = dinv[node];
    float2 bb = *(const float2*)(bias + 2 * l);
    float ax = fmaf(dn, (a0x + a1x) + (a2x + a3x), bb.x);
    float ay = fmaf(dn, (a0y + a1y) + (a2y + a3y), bb.y);
    float p = ax * ax + ay * ay;
#pragma unroll
    for (int m = 1; m < 64; m <<= 1) p += __shfl_xor(p, m);
    float factor = (p / (1.0f + p)) * rsqrtf(p + 1e-8f);
    xv = make_float2(ax * factor, ay * factor);
    float2 wa = *(const float2*)(watt + 2 * l);
    att = xv.x * wa.x + xv.y * wa.y;
#pragma unroll
    for (int m = 1; m < 64; m <<= 1) att += __shfl_xor(att, m);
    g = batch[node];
    if (GEMM) {
      // H_next[node][2l,2l+1] = sum_k (dn*x_k) * W16[k][2l,2l+1]
      float xs0 = xv.x * dn, xs1 = xv.y * dn;
      float acc0 = 0.f, acc1 = 0.f;
#pragma unroll 4
      for (int kl = 0; kl < 64; kl++) {
        float xb0 = __shfl(xs0, kl);            // feature k=2kl
        float xb1 = __shfl(xs1, kl);            // feature k=2kl+1
        float2 fa = __half22float2(W16[kl * 128 + l]);        // row 2kl, cols 2l,2l+1
        float2 fb = __half22float2(W16[kl * 128 + 64 + l]);   // row 2kl+1
        acc0 = fmaf(xb0, fa.x, acc0); acc1 = fmaf(xb0, fa.y, acc1);
        acc0 = fmaf(xb1, fb.x, acc0); acc1 = fmaf(xb1, fb.y, acc1);
      }
      Hnext[(size_t)node * 64 + l] = __floats2half2_rn(acc0, acc1);
    }
  }
  if (valid) {
    int fb = 2 * l;
    if (g == g0) {
      atomicAdd(&l_ws[fb + 0], att * xv.x);
      atomicAdd(&l_ws[fb + 1], att * xv.y);
      atomicAdd(&l_ms[fb + 0], xv.x);
      atomicAdd(&l_ms[fb + 1], xv.y);
      atomicMax(&l_mx[fb + 0], encf(xv.x));
      atomicMax(&l_mx[fb + 1], encf(xv.y));
    } else {  // rare: graph boundary inside block
      int base = g * 128 + fb;
      atomicAdd(wsum + base + 0, att * xv.x);
      atomicAdd(wsum + base + 1, att * xv.y);
      atomicAdd(msum + base + 0, xv.x);
      atomicAdd(msum + base + 1, xv.y);
      atomicMax(maxenc + base + 0, encf(xv.x));
      atomicMax(maxenc + base + 1, encf(xv.y));
    }
  }
  __syncthreads();
  if (t < 128) {
    int base = g0 * 128 + t;
    atomicAdd(wsum + base, l_ws[t]);
    atomicAdd(msum + base, l_ms[t]);
    unsigned u = l_mx[t];
    if (u) atomicMax(maxenc + base, u);
  }
}

// ---------- MLP head + log_softmax, one block per graph ----------
__global__ __launch_bounds__(128) void k_head(const float* __restrict__ wsum,
                                              const float* __restrict__ msum,
                                              const unsigned* __restrict__ maxenc,
                                              const float* __restrict__ countsf,
                                              const float* __restrict__ l1w,
                                              const float* __restrict__ l1b,
                                              const float* __restrict__ l2w,
                                              const float* __restrict__ l2b,
                                              float* __restrict__ out) {
  int g = blockIdx.x, t = threadIdx.x;
  __shared__ float rep[384];
  __shared__ float h1[128];
  __shared__ float lg[NCLS];
  float invc = 1.0f / countsf[g];
  rep[t] = wsum[g * 128 + t];
  rep[128 + t] = msum[g * 128 + t] * invc;
  rep[256 + t] = decf(maxenc[g * 128 + t]) +
                 decf(maxenc[NGRAPH * 128 + g * 128 + t]) +
                 decf(maxenc[2 * NGRAPH * 128 + g * 128 + t]);
  __syncthreads();
  float acc = l1b[t];
  for (int k = 0; k < 384; k++) acc = fmaf(rep[k], l1w[k * 128 + t], acc);
  h1[t] = fmaxf(acc, 0.f);
  __syncthreads();
  if (t < NCLS) {
    float a = l2b[t];
    for (int j = 0; j < 128; j++) a = fmaf(h1[j], l2w[j * NCLS + t], a);
    lg[t] = a;
  }
  __syncthreads();
  if (t < NCLS) {
    float m = lg[0];
    for (int c = 1; c < NCLS; c++) m = fmaxf(m, lg[c]);
    float s = 0.f;
    for (int c = 0; c < NCLS; c++) s += expf(lg[c] - m);
    out[g * NCLS + t] = lg[t] - m - logf(s);
  }
}

extern "C" void kernel_launch(void* const* d_in, const int* in_sizes, int n_in,
                              void* d_out, int out_size, void* d_ws, size_t ws_size,
                              hipStream_t stream) {
  const float* x      = (const float*)d_in[0];
  const int* edge     = (const int*)d_in[1];
  const int* batch    = (const int*)d_in[2];
  const float* gamma  = (const float*)d_in[3];
  const float* beta   = (const float*)d_in[4];
  const float* gcn_w  = (const float*)d_in[5];
  const float* gcn_b  = (const float*)d_in[6];
  const float* w_att  = (const float*)d_in[7];
  const float* l1w    = (const float*)d_in[8];
  const float* l1b    = (const float*)d_in[9];
  const float* l2w    = (const float*)d_in[10];
  const float* l2b    = (const float*)d_in[11];
  float* out          = (float*)d_out;

  const int N = in_sizes[0] / FDIM;   // 50000
  const int E = in_sizes[1] / 2;      // 640000
  const int* esrc = edge;
  const int* edst = edge + E;

  char* w = (char*)d_ws;
  size_t off = 0;
  auto alloc = [&](size_t bytes) {
    void* p = (void*)(w + off);
    off += (bytes + 1023) & ~(size_t)1023;
    return p;
  };
  __half* H0 = (__half*)alloc((size_t)N * FDIM * 2);
  __half* H1 = (__half*)alloc((size_t)N * FDIM * 2);
  // zero zone start
  size_t zoff = off;
  int* cursor      = (int*)alloc((size_t)N * CSTRIDE * 4);   // 1 counter per cache line
  int* gstart      = (int*)alloc(NGRAPH * 4);
  int* gend        = (int*)alloc(NGRAPH * 4);
  float* wsum      = (float*)alloc(NGRAPH * FDIM * 4);
  float* msum      = (float*)alloc(NGRAPH * FDIM * 4);
  unsigned* maxenc = (unsigned*)alloc((size_t)3 * NGRAPH * FDIM * 4);  // per-layer
  size_t zbytes = off - zoff;
  // non-zeroed
  float* partS    = (float*)alloc((size_t)STATS_BLOCKS * FDIM * 4);
  float* partQ    = (float*)alloc((size_t)STATS_BLOCKS * FDIM * 4);
  int* deg        = (int*)alloc((size_t)N * 4);
  float* dinv     = (float*)alloc((size_t)N * 4);
  float* countsf  = (float*)alloc(NGRAPH * 4);
  float* aff_a    = (float*)alloc(FDIM * 4);
  float* aff_b    = (float*)alloc(FDIM * 4);
  __half* W16     = (__half*)alloc((size_t)2 * FDIM * FDIM * 2);  // W1,W2 in fp16
  int* ell_src    = (int*)alloc((size_t)N * ELLCAP * 4 + 1024);  // +slack for int4 overread
  (void)ws_size; (void)n_in; (void)out_size;

  hipMemsetAsync(w + zoff, 0, zbytes, stream);

  const int nbN = (N + 255) / 256;
  const int nbE = (E + 255) / 256;
  const int total4 = N * FDIM / 4;
  const int gemmBlocks = (N + 63) / 64;
  const int aggBlocks = (N + AGG_NODES - 1) / AGG_NODES;
  const int nScaleBlocks = (N + 3) / 4;
  const int nbW = (2 * FDIM * FDIM + 255) / 256;

  k_bn<<<STATS_BLOCKS + nbN + nbW, 256, 0, stream>>>(x, partS, partQ, total4, batch,
                                                     gstart, gend, gcn_w, W16, nbN, N);
  k_aff<<<1, 256, 0, stream>>>(partS, partQ, gamma, beta, aff_a, aff_b,
                               gstart, gend, countsf, N);
  k_mega<<<gemmBlocks + nbE, 256, 0, stream>>>(x, aff_a, aff_b, gcn_w, H0, gemmBlocks,
                                               esrc, edst, cursor, ell_src, E, N);
  k_post<<<nScaleBlocks + nbN, 256, 0, stream>>>(cursor, deg, dinv, (__half2*)H0,
                                                 nScaleBlocks, N);

  // layer 0: read H0, fused-gemm W1 -> H1
  k_agg_squash<1><<<aggBlocks, 512, 0, stream>>>((const __half2*)H0, (__half2*)H1,
                                                 (const __half2*)W16, deg, ell_src,
                                                 gcn_b, w_att, batch, dinv,
                                                 wsum, msum, maxenc, N);
  // layer 1: read H1, fused-gemm W2 -> H0
  k_agg_squash<1><<<aggBlocks, 512, 0, stream>>>((const __half2*)H1, (__half2*)H0,
                                                 (const __half2*)(W16 + FDIM * FDIM),
                                                 deg, ell_src,
                                                 gcn_b + FDIM, w_att + FDIM, batch, dinv,
                                                 wsum, msum,
                                                 maxenc + (size_t)NGRAPH * FDIM, N);
  // layer 2: read H0, no gemm
  k_agg_squash<0><<<aggBlocks, 512, 0, stream>>>((const __half2*)H0, nullptr, nullptr,
                                                 deg, ell_src,
                                                 gcn_b + 2 * FDIM, w_att + 2 * FDIM,
                                                 batch, dinv, wsum, msum,
                                                 maxenc + (size_t)2 * NGRAPH * FDIM, N);
  k_head<<<NGRAPH, 128, 0, stream>>>(wsum, msum, maxenc, countsf, l1w, l1b, l2w, l2b, out);
}

// Round 13
// 468.194 us; speedup vs baseline: 1.1832x; 1.1832x over previous
//
#include <hip/hip_runtime.h>
#include <hip/hip_fp16.h>

#define FDIM 128
#define NGRAPH 256
#define NCLS 10
#define AGG_NODES 8     // nodes per block in k_agg_squash (512 threads = 8 waves)
#define STATS_BLOCKS 256
#define CSTRIDE 16      // ints per counter slot (one 64B line) — kills per-line atomic serialization
#define ELLCAP 64       // slots per node; max degree (Poisson mean 12.8) is far below this

typedef __attribute__((ext_vector_type(8))) _Float16 half8;
typedef __attribute__((ext_vector_type(4))) float floatx4;

__device__ __forceinline__ unsigned encf(float f) {
  unsigned b = __float_as_uint(f);
  return (b & 0x80000000u) ? ~b : (b | 0x80000000u);
}
__device__ __forceinline__ float decf(unsigned u) {
  if (u == 0u) return 0.f;  // empty segment -> 0 (matches isfinite->0)
  return (u & 0x80000000u) ? __uint_as_float(u & 0x7FFFFFFFu) : __uint_as_float(~u);
}

// ---------- BN partial sums (blocks 0..255) + batch bounds + W1/W2 -> fp16 TRANSPOSED ----------
__global__ __launch_bounds__(256) void k_bn(const float* __restrict__ x,
                                            float* __restrict__ partS,
                                            float* __restrict__ partQ, int total4,
                                            const int* __restrict__ batch,
                                            int* __restrict__ gstart,
                                            int* __restrict__ gend,
                                            const float* __restrict__ gcn_w,
                                            __half* __restrict__ W16T,
                                            int nbN, int N) {
  int t = threadIdx.x;
  if (blockIdx.x >= STATS_BLOCKS + nbN) {
    // WT[l][n][k] = W[l+1][k][n], fp16 — 2*128*128 elems
    int idx = (blockIdx.x - STATS_BLOCKS - nbN) * 256 + t;
    if (idx < 2 * FDIM * FDIM) {
      int l = idx >> 14;
      int rem = idx & 16383;
      int n = rem >> 7;
      int k = rem & 127;
      W16T[idx] = __float2half(gcn_w[(1 + l) * FDIM * FDIM + k * FDIM + n]);
    }
    return;
  }
  if (blockIdx.x >= STATS_BLOCKS) {
    int e = (blockIdx.x - STATS_BLOCKS) * 256 + t;
    if (e < N) {
      int b = batch[e];
      if (e == 0 || batch[e - 1] != b) gstart[b] = e;
      if (e == N - 1) gend[b] = N;
      else if (batch[e + 1] != b) gend[b] = e + 1;
    }
    return;
  }
  __shared__ float ss[1024];
  __shared__ float sq[1024];
  float s0 = 0, s1 = 0, s2 = 0, s3 = 0, q0 = 0, q1 = 0, q2 = 0, q3 = 0;
  for (int i = blockIdx.x * 256 + t; i < total4; i += STATS_BLOCKS * 256) {
    float4 v = ((const float4*)x)[i];
    s0 += v.x; q0 += v.x * v.x;
    s1 += v.y; q1 += v.y * v.y;
    s2 += v.z; q2 += v.z * v.z;
    s3 += v.w; q3 += v.w * v.w;
  }
  int fb = (t & 31) * 4, slot = t >> 5;
  ss[slot * 128 + fb + 0] = s0; ss[slot * 128 + fb + 1] = s1;
  ss[slot * 128 + fb + 2] = s2; ss[slot * 128 + fb + 3] = s3;
  sq[slot * 128 + fb + 0] = q0; sq[slot * 128 + fb + 1] = q1;
  sq[slot * 128 + fb + 2] = q2; sq[slot * 128 + fb + 3] = q3;
  __syncthreads();
  if (t < 128) {
    float a = 0, b = 0;
    for (int s = 0; s < 8; s++) { a += ss[s * 128 + t]; b += sq[s * 128 + t]; }
    partS[blockIdx.x * 128 + t] = a;
    partQ[blockIdx.x * 128 + t] = b;
  }
}

// ---------- tiny: reduce BN partials -> affine; counts from bounds ----------
__global__ __launch_bounds__(256) void k_aff(const float* __restrict__ partS,
                                             const float* __restrict__ partQ,
                                             const float* __restrict__ gamma,
                                             const float* __restrict__ beta,
                                             float* __restrict__ aff_a,
                                             float* __restrict__ aff_b,
                                             const int* __restrict__ gstart,
                                             const int* __restrict__ gend,
                                             float* __restrict__ countsf, int N) {
  int t = threadIdx.x;
  if (t < NGRAPH) countsf[t] = fmaxf((float)(gend[t] - gstart[t]), 1.0f);
  if (t < FDIM) {
    float a = 0.f, b = 0.f;
    for (int bk = 0; bk < STATS_BLOCKS; bk++) {
      a += partS[bk * 128 + t];
      b += partQ[bk * 128 + t];
    }
    float invN = 1.0f / (float)N;
    float mu = a * invN;
    float var = b * invN - mu * mu;
    float inv = rsqrtf(var + 1e-5f);
    float ga = gamma[t] * inv;
    aff_a[t] = ga;
    aff_b[t] = beta[t] - mu * ga;
  }
}

// ---------- MEGA: gemm0 Hraw=(aff*x)@W (blocks < gemmBlocks, K-tiled 16KB LDS)
// ----------       + ELL edge ingest (remaining blocks) — the two overlap ----------
__global__ __launch_bounds__(256) void k_mega(const float* __restrict__ x,
                                              const float* __restrict__ aff_a,
                                              const float* __restrict__ aff_b,
                                              const float* __restrict__ W,
                                              __half* __restrict__ Hout, int gemmBlocks,
                                              const int* __restrict__ src,
                                              const int* __restrict__ dst,
                                              int* __restrict__ cursor,
                                              int* __restrict__ ell_src, int E, int N) {
  int t = threadIdx.x;
  if (blockIdx.x >= gemmBlocks) {
    int e = (blockIdx.x - gemmBlocks) * 256 + t;
    if (e < E) {
      int s = src[e], d = dst[e];
      if (s != d) {
        int p = atomicAdd(cursor + (size_t)d * CSTRIDE, 1);
        if (p < ELLCAP) ell_src[(size_t)d * ELLCAP + p] = s;
      }
    }
    return;  // edge blocks never reach the barriers below
  }
  __shared__ float sW[32 * 128];   // 16 KB K-tile of W
  __shared__ float sA[128];
  __shared__ float sB[128];
  if (t < 128) { sA[t] = aff_a[t]; sB[t] = aff_b[t]; }
  int tx = t & 31, ty = t >> 5;
  int nodeBase = blockIdx.x * 64 + ty * 8;
  int nidx[8];
#pragma unroll
  for (int i = 0; i < 8; i++) nidx[i] = min(nodeBase + i, N - 1);
  float acc[8][4];
#pragma unroll
  for (int i = 0; i < 8; i++) { acc[i][0] = acc[i][1] = acc[i][2] = acc[i][3] = 0.f; }
  for (int kk = 0; kk < 128; kk += 32) {
    __syncthreads();
#pragma unroll
    for (int i = 0; i < 4; i++) {
      int idx = t * 4 + i * 1024;
      *(float4*)(sW + idx) = *(const float4*)(W + kk * 128 + idx);
    }
    __syncthreads();
#pragma unroll 2
    for (int k2 = 0; k2 < 32; k2 += 4) {
      int k = kk + k2;
      float4 b0 = *(const float4*)(sW + (k2 + 0) * 128 + tx * 4);
      float4 b1 = *(const float4*)(sW + (k2 + 1) * 128 + tx * 4);
      float4 b2 = *(const float4*)(sW + (k2 + 2) * 128 + tx * 4);
      float4 b3 = *(const float4*)(sW + (k2 + 3) * 128 + tx * 4);
      float4 va = *(const float4*)(sA + k);
      float4 vb = *(const float4*)(sB + k);
#pragma unroll
      for (int i = 0; i < 8; i++) {
        float4 a = *(const float4*)(x + (size_t)nidx[i] * 128 + k);
        a.x = fmaf(a.x, va.x, vb.x);
        a.y = fmaf(a.y, va.y, vb.y);
        a.z = fmaf(a.z, va.z, vb.z);
        a.w = fmaf(a.w, va.w, vb.w);
        acc[i][0] = fmaf(a.w, b3.x, fmaf(a.z, b2.x, fmaf(a.y, b1.x, fmaf(a.x, b0.x, acc[i][0]))));
        acc[i][1] = fmaf(a.w, b3.y, fmaf(a.z, b2.y, fmaf(a.y, b1.y, fmaf(a.x, b0.y, acc[i][1]))));
        acc[i][2] = fmaf(a.w, b3.z, fmaf(a.z, b2.z, fmaf(a.y, b1.z, fmaf(a.x, b0.z, acc[i][2]))));
        acc[i][3] = fmaf(a.w, b3.w, fmaf(a.z, b2.w, fmaf(a.y, b1.w, fmaf(a.x, b0.w, acc[i][3]))));
      }
    }
  }
#pragma unroll
  for (int i = 0; i < 8; i++) {
    int node = nodeBase + i;
    if (node < N) {
      __half2 p0 = __floats2half2_rn(acc[i][0], acc[i][1]);
      __half2 p1 = __floats2half2_rn(acc[i][2], acc[i][3]);
      uint2 st;
      st.x = *(unsigned*)&p0;
      st.y = *(unsigned*)&p1;
      *(uint2*)(Hout + (size_t)node * 128 + tx * 4) = st;
    }
  }
}

// ---------- post: scale H by dinv (from cursor) + write deg/dinv arrays ----------
__global__ __launch_bounds__(256) void k_post(const int* __restrict__ cursor,
                                              int* __restrict__ deg,
                                              float* __restrict__ dinv,
                                              __half2* __restrict__ H,
                                              int nScaleBlocks, int N) {
  int t = threadIdx.x;
  if (blockIdx.x < nScaleBlocks) {
    int wv = t >> 6, l = t & 63;
    int row = blockIdx.x * 4 + wv;
    if (row >= N) return;
    float dv = rsqrtf(1.0f + (float)min(cursor[(size_t)row * CSTRIDE], ELLCAP));
    float2 f = __half22float2(H[(size_t)row * 64 + l]);
    H[(size_t)row * 64 + l] = __floats2half2_rn(f.x * dv, f.y * dv);
  } else {
    int i = (blockIdx.x - nScaleBlocks) * 256 + t;
    if (i < N) {
      int d = min(cursor[(size_t)i * CSTRIDE], ELLCAP);
      deg[i] = d;
      dinv[i] = rsqrtf(1.0f + (float)d);
    }
  }
}

// ---------- GEMM layers 1,2 via MFMA: H = Xh @ W  (Xh fp16, dinv pre-folded) ----------
// One wave computes 16 nodes x 128 cols. A-frag: Xh[nodeBase+(lane&15)][ks*32+quad*8..+7]
// B-frag: WT[ct*16+(lane&15)][ks*32+quad*8..+7]  (WT = W^T fp16 -> contiguous loads)
// C/D: col=ct*16+(lane&15), row=quad*4+reg  [guide-verified layouts]
__global__ __launch_bounds__(256) void k_gemm_mfma(const _Float16* __restrict__ Xh,
                                                   const _Float16* __restrict__ WT,
                                                   _Float16* __restrict__ Hout, int N) {
  int t = threadIdx.x;
  int wave = t >> 6, lane = t & 63;
  int r16 = lane & 15, quad = lane >> 4;
  int nodeBase = (blockIdx.x * 4 + wave) * 16;
  if (nodeBase >= N) return;
  int arow = min(nodeBase + r16, N - 1);
  half8 afrag[4];
#pragma unroll
  for (int ks = 0; ks < 4; ks++)
    afrag[ks] = *(const half8*)(Xh + (size_t)arow * 128 + ks * 32 + quad * 8);
  floatx4 acc[8];
#pragma unroll
  for (int ct = 0; ct < 8; ct++) acc[ct] = (floatx4){0.f, 0.f, 0.f, 0.f};
#pragma unroll
  for (int ct = 0; ct < 8; ct++) {
    int ncol = ct * 16 + r16;
#pragma unroll
    for (int ks = 0; ks < 4; ks++) {
      half8 bfrag = *(const half8*)(WT + (size_t)ncol * 128 + ks * 32 + quad * 8);
      acc[ct] = __builtin_amdgcn_mfma_f32_16x16x32_f16(afrag[ks], bfrag, acc[ct], 0, 0, 0);
    }
  }
#pragma unroll
  for (int ct = 0; ct < 8; ct++) {
    int col = ct * 16 + r16;
#pragma unroll
    for (int j = 0; j < 4; j++) {
      int node = nodeBase + quad * 4 + j;
      if (node < N) Hout[(size_t)node * 128 + col] = (_Float16)acc[ct][j];
    }
  }
}

// ---------- fused: ELL aggregate + bias + squash + attention + graph scatter ----------
// One wave per dst node; lane l owns features 2l,2l+1. ILP-4 padded edge loop;
// per-iter: ONE broadcast int4 (src indices) + 4 independent H'-row gathers.
// H' carries src-side dinv. WRITE_X: store X scaled by dinv[node] (feeds next gemm).
template <int WRITE_X>
__global__ __launch_bounds__(512) void k_agg_squash(const __half2* __restrict__ H,
                                                    const int* __restrict__ deg,
                                                    const int* __restrict__ ell_src,
                                                    const float* __restrict__ bias,
                                                    const float* __restrict__ watt,
                                                    const int* __restrict__ batch,
                                                    const float* __restrict__ dinv,
                                                    __half2* __restrict__ Xh,
                                                    float* __restrict__ wsum,
                                                    float* __restrict__ msum,
                                                    unsigned* __restrict__ maxenc, int N) {
  __shared__ float l_ws[128];
  __shared__ float l_ms[128];
  __shared__ unsigned l_mx[128];
  int t = threadIdx.x;
  if (t < 128) { l_ws[t] = 0.f; l_ms[t] = 0.f; l_mx[t] = 0u; }
  __syncthreads();

  int wv = t >> 6, l = t & 63;
  int node = blockIdx.x * AGG_NODES + wv;
  int g0 = batch[blockIdx.x * AGG_NODES];
  bool valid = node < N;
  float2 xv = make_float2(0.f, 0.f);
  float att = 0.f;
  int g = g0;
  if (valid) {
    float2 h0 = __half22float2(H[(size_t)node * 64 + l]);
    float a0x = h0.x, a0y = h0.y;
    float a1x = 0.f, a1y = 0.f, a2x = 0.f, a2y = 0.f, a3x = 0.f, a3y = 0.f;
    size_t base = (size_t)node * ELLCAP;
    int cnt = deg[node];
    for (int j = 0; j < cnt; j += 4) {
      int4 ss = *(const int4*)(ell_src + base + j);   // broadcast 16B
      bool v1 = (j + 1 < cnt), v2 = (j + 2 < cnt), v3 = (j + 3 < cnt);
      int s0 = ss.x;
      int s1 = v1 ? ss.y : 0;
      int s2 = v2 ? ss.z : 0;
      int s3 = v3 ? ss.w : 0;
      float m1 = v1 ? 1.f : 0.f;
      float m2 = v2 ? 1.f : 0.f;
      float m3 = v3 ? 1.f : 0.f;
      float2 r0 = __half22float2(H[(size_t)s0 * 64 + l]);
      float2 r1 = __half22float2(H[(size_t)s1 * 64 + l]);
      float2 r2 = __half22float2(H[(size_t)s2 * 64 + l]);
      float2 r3 = __half22float2(H[(size_t)s3 * 64 + l]);
      a0x += r0.x;               a0y += r0.y;
      a1x = fmaf(m1, r1.x, a1x); a1y = fmaf(m1, r1.y, a1y);
      a2x = fmaf(m2, r2.x, a2x); a2y = fmaf(m2, r2.y, a2y);
      a3x = fmaf(m3, r3.x, a3x); a3y = fmaf(m3, r3.y, a3y);
    }
    float dn = dinv[node];
    float2 bb = *(const float2*)(bias + 2 * l);
    float ax = fmaf(dn, (a0x + a1x) + (a2x + a3x), bb.x);
    float ay = fmaf(dn, (a0y + a1y) + (a2y + a3y), bb.y);
    float p = ax * ax + ay * ay;
#pragma unroll
    for (int m = 1; m < 64; m <<= 1) p += __shfl_xor(p, m);
    float factor = (p / (1.0f + p)) * rsqrtf(p + 1e-8f);
    xv = make_float2(ax * factor, ay * factor);
    if (WRITE_X) Xh[(size_t)node * 64 + l] = __floats2half2_rn(xv.x * dn, xv.y * dn);
    float2 wa = *(const float2*)(watt + 2 * l);
    att = xv.x * wa.x + xv.y * wa.y;
#pragma unroll
    for (int m = 1; m < 64; m <<= 1) att += __shfl_xor(att, m);
    g = batch[node];
  }
  if (valid) {
    int fb = 2 * l;
    if (g == g0) {
      atomicAdd(&l_ws[fb + 0], att * xv.x);
      atomicAdd(&l_ws[fb + 1], att * xv.y);
      atomicAdd(&l_ms[fb + 0], xv.x);
      atomicAdd(&l_ms[fb + 1], xv.y);
      atomicMax(&l_mx[fb + 0], encf(xv.x));
      atomicMax(&l_mx[fb + 1], encf(xv.y));
    } else {  // rare: graph boundary inside block
      int base = g * 128 + fb;
      atomicAdd(wsum + base + 0, att * xv.x);
      atomicAdd(wsum + base + 1, att * xv.y);
      atomicAdd(msum + base + 0, xv.x);
      atomicAdd(msum + base + 1, xv.y);
      atomicMax(maxenc + base + 0, encf(xv.x));
      atomicMax(maxenc + base + 1, encf(xv.y));
    }
  }
  __syncthreads();
  if (t < 128) {
    int base = g0 * 128 + t;
    atomicAdd(wsum + base, l_ws[t]);
    atomicAdd(msum + base, l_ms[t]);
    unsigned u = l_mx[t];
    if (u) atomicMax(maxenc + base, u);
  }
}

// ---------- MLP head + log_softmax, one block per graph ----------
__global__ __launch_bounds__(128) void k_head(const float* __restrict__ wsum,
                                              const float* __restrict__ msum,
                                              const unsigned* __restrict__ maxenc,
                                              const float* __restrict__ countsf,
                                              const float* __restrict__ l1w,
                                              const float* __restrict__ l1b,
                                              const float* __restrict__ l2w,
                                              const float* __restrict__ l2b,
                                              float* __restrict__ out) {
  int g = blockIdx.x, t = threadIdx.x;
  __shared__ float rep[384];
  __shared__ float h1[128];
  __shared__ float lg[NCLS];
  float invc = 1.0f / countsf[g];
  rep[t] = wsum[g * 128 + t];
  rep[128 + t] = msum[g * 128 + t] * invc;
  rep[256 + t] = decf(maxenc[g * 128 + t]) +
                 decf(maxenc[NGRAPH * 128 + g * 128 + t]) +
                 decf(maxenc[2 * NGRAPH * 128 + g * 128 + t]);
  __syncthreads();
  float acc = l1b[t];
  for (int k = 0; k < 384; k++) acc = fmaf(rep[k], l1w[k * 128 + t], acc);
  h1[t] = fmaxf(acc, 0.f);
  __syncthreads();
  if (t < NCLS) {
    float a = l2b[t];
    for (int j = 0; j < 128; j++) a = fmaf(h1[j], l2w[j * NCLS + t], a);
    lg[t] = a;
  }
  __syncthreads();
  if (t < NCLS) {
    float m = lg[0];
    for (int c = 1; c < NCLS; c++) m = fmaxf(m, lg[c]);
    float s = 0.f;
    for (int c = 0; c < NCLS; c++) s += expf(lg[c] - m);
    out[g * NCLS + t] = lg[t] - m - logf(s);
  }
}

extern "C" void kernel_launch(void* const* d_in, const int* in_sizes, int n_in,
                              void* d_out, int out_size, void* d_ws, size_t ws_size,
                              hipStream_t stream) {
  const float* x      = (const float*)d_in[0];
  const int* edge     = (const int*)d_in[1];
  const int* batch    = (const int*)d_in[2];
  const float* gamma  = (const float*)d_in[3];
  const float* beta   = (const float*)d_in[4];
  const float* gcn_w  = (const float*)d_in[5];
  const float* gcn_b  = (const float*)d_in[6];
  const float* w_att  = (const float*)d_in[7];
  const float* l1w    = (const float*)d_in[8];
  const float* l1b    = (const float*)d_in[9];
  const float* l2w    = (const float*)d_in[10];
  const float* l2b    = (const float*)d_in[11];
  float* out          = (float*)d_out;

  const int N = in_sizes[0] / FDIM;   // 50000
  const int E = in_sizes[1] / 2;      // 640000
  const int* esrc = edge;
  const int* edst = edge + E;

  char* w = (char*)d_ws;
  size_t off = 0;
  auto alloc = [&](size_t bytes) {
    void* p = (void*)(w + off);
    off += (bytes + 1023) & ~(size_t)1023;
    return p;
  };
  __half* Xh = (__half*)alloc((size_t)N * FDIM * 2);
  __half* H  = (__half*)alloc((size_t)N * FDIM * 2);
  // zero zone start
  size_t zoff = off;
  int* cursor      = (int*)alloc((size_t)N * CSTRIDE * 4);   // 1 counter per cache line
  int* gstart      = (int*)alloc(NGRAPH * 4);
  int* gend        = (int*)alloc(NGRAPH * 4);
  float* wsum      = (float*)alloc(NGRAPH * FDIM * 4);
  float* msum      = (float*)alloc(NGRAPH * FDIM * 4);
  unsigned* maxenc = (unsigned*)alloc((size_t)3 * NGRAPH * FDIM * 4);  // per-layer
  size_t zbytes = off - zoff;
  // non-zeroed
  float* partS    = (float*)alloc((size_t)STATS_BLOCKS * FDIM * 4);
  float* partQ    = (float*)alloc((size_t)STATS_BLOCKS * FDIM * 4);
  int* deg        = (int*)alloc((size_t)N * 4);
  float* dinv     = (float*)alloc((size_t)N * 4);
  float* countsf  = (float*)alloc(NGRAPH * 4);
  float* aff_a    = (float*)alloc(FDIM * 4);
  float* aff_b    = (float*)alloc(FDIM * 4);
  __half* W16T    = (__half*)alloc((size_t)2 * FDIM * FDIM * 2);  // W1^T,W2^T fp16
  int* ell_src    = (int*)alloc((size_t)N * ELLCAP * 4 + 1024);  // +slack for int4 overread
  (void)ws_size; (void)n_in; (void)out_size;

  hipMemsetAsync(w + zoff, 0, zbytes, stream);

  const int nbN = (N + 255) / 256;
  const int nbE = (E + 255) / 256;
  const int total4 = N * FDIM / 4;
  const int gemmBlocks = (N + 63) / 64;
  const int aggBlocks = (N + AGG_NODES - 1) / AGG_NODES;
  const int nScaleBlocks = (N + 3) / 4;
  const int nbW = (2 * FDIM * FDIM + 255) / 256;
  const int mfmaBlocks = (N + 63) / 64;   // 16 nodes/wave, 4 waves/block

  k_bn<<<STATS_BLOCKS + nbN + nbW, 256, 0, stream>>>(x, partS, partQ, total4, batch,
                                                     gstart, gend, gcn_w, W16T, nbN, N);
  k_aff<<<1, 256, 0, stream>>>(partS, partQ, gamma, beta, aff_a, aff_b,
                               gstart, gend, countsf, N);
  k_mega<<<gemmBlocks + nbE, 256, 0, stream>>>(x, aff_a, aff_b, gcn_w, H, gemmBlocks,
                                               esrc, edst, cursor, ell_src, E, N);
  k_post<<<nScaleBlocks + nbN, 256, 0, stream>>>(cursor, deg, dinv, (__half2*)H,
                                                 nScaleBlocks, N);

  for (int layer = 0; layer < 3; layer++) {
    if (layer > 0)
      k_gemm_mfma<<<mfmaBlocks, 256, 0, stream>>>((const _Float16*)Xh,
                                                  (const _Float16*)(W16T + (size_t)(layer - 1) * FDIM * FDIM),
                                                  (_Float16*)H, N);
    if (layer < 2)
      k_agg_squash<1><<<aggBlocks, 512, 0, stream>>>((const __half2*)H, deg, ell_src,
                                                     gcn_b + layer * FDIM,
                                                     w_att + layer * FDIM, batch, dinv,
                                                     (__half2*)Xh, wsum, msum,
                                                     maxenc + (size_t)layer * NGRAPH * FDIM, N);
    else
      k_agg_squash<0><<<aggBlocks, 512, 0, stream>>>((const __half2*)H, deg, ell_src,
                                                     gcn_b + layer * FDIM,
                                                     w_att + layer * FDIM, batch, dinv,
                                                     (__half2*)Xh, wsum, msum,
                                                     maxenc + (size_t)layer * NGRAPH * FDIM, N);
  }
  k_head<<<NGRAPH, 128, 0, stream>>>(wsum, msum, maxenc, countsf, l1w, l1b, l2w, l2b, out);
}

// Round 14
// 450.070 us; speedup vs baseline: 1.2308x; 1.0403x over previous
//
#include <hip/hip_runtime.h>
#include <hip/hip_fp16.h>

#define FDIM 128
#define NGRAPH 256
#define NCLS 10
#define AGG_NODES 8     // nodes per block in k_agg_squash (512 threads = 8 waves)
#define STATS_BLOCKS 256
#define CSTRIDE 16      // ints per counter slot (one 64B line) — kills per-line atomic serialization
#define ELLCAP 64       // slots per node; max degree (Poisson mean 12.8) is far below this
#define SXPITCH 136     // LDS X row pitch in halfs: 272B = 17*16B -> aligned, 2-way-conflict-free

typedef __attribute__((ext_vector_type(8))) _Float16 half8;
typedef __attribute__((ext_vector_type(4))) float floatx4;

__device__ __forceinline__ unsigned encf(float f) {
  unsigned b = __float_as_uint(f);
  return (b & 0x80000000u) ? ~b : (b | 0x80000000u);
}
__device__ __forceinline__ float decf(unsigned u) {
  if (u == 0u) return 0.f;  // empty segment -> 0 (matches isfinite->0)
  return (u & 0x80000000u) ? __uint_as_float(u & 0x7FFFFFFFu) : __uint_as_float(~u);
}

// ---------- BN partial sums (blocks 0..255) + batch bounds + W1/W2 -> fp16 TRANSPOSED ----------
__global__ __launch_bounds__(256) void k_bn(const float* __restrict__ x,
                                            float* __restrict__ partS,
                                            float* __restrict__ partQ, int total4,
                                            const int* __restrict__ batch,
                                            int* __restrict__ gstart,
                                            int* __restrict__ gend,
                                            const float* __restrict__ gcn_w,
                                            __half* __restrict__ W16T,
                                            int nbN, int N) {
  int t = threadIdx.x;
  if (blockIdx.x >= STATS_BLOCKS + nbN) {
    // WT[l][n][k] = W[l+1][k][n], fp16 — 2*128*128 elems
    int idx = (blockIdx.x - STATS_BLOCKS - nbN) * 256 + t;
    if (idx < 2 * FDIM * FDIM) {
      int l = idx >> 14;
      int rem = idx & 16383;
      int n = rem >> 7;
      int k = rem & 127;
      W16T[idx] = __float2half(gcn_w[(1 + l) * FDIM * FDIM + k * FDIM + n]);
    }
    return;
  }
  if (blockIdx.x >= STATS_BLOCKS) {
    int e = (blockIdx.x - STATS_BLOCKS) * 256 + t;
    if (e < N) {
      int b = batch[e];
      if (e == 0 || batch[e - 1] != b) gstart[b] = e;
      if (e == N - 1) gend[b] = N;
      else if (batch[e + 1] != b) gend[b] = e + 1;
    }
    return;
  }
  __shared__ float ss[1024];
  __shared__ float sq[1024];
  float s0 = 0, s1 = 0, s2 = 0, s3 = 0, q0 = 0, q1 = 0, q2 = 0, q3 = 0;
  for (int i = blockIdx.x * 256 + t; i < total4; i += STATS_BLOCKS * 256) {
    float4 v = ((const float4*)x)[i];
    s0 += v.x; q0 += v.x * v.x;
    s1 += v.y; q1 += v.y * v.y;
    s2 += v.z; q2 += v.z * v.z;
    s3 += v.w; q3 += v.w * v.w;
  }
  int fb = (t & 31) * 4, slot = t >> 5;
  ss[slot * 128 + fb + 0] = s0; ss[slot * 128 + fb + 1] = s1;
  ss[slot * 128 + fb + 2] = s2; ss[slot * 128 + fb + 3] = s3;
  sq[slot * 128 + fb + 0] = q0; sq[slot * 128 + fb + 1] = q1;
  sq[slot * 128 + fb + 2] = q2; sq[slot * 128 + fb + 3] = q3;
  __syncthreads();
  if (t < 128) {
    float a = 0, b = 0;
    for (int s = 0; s < 8; s++) { a += ss[s * 128 + t]; b += sq[s * 128 + t]; }
    partS[blockIdx.x * 128 + t] = a;
    partQ[blockIdx.x * 128 + t] = b;
  }
}

// ---------- tiny: reduce BN partials -> affine; counts from bounds ----------
__global__ __launch_bounds__(256) void k_aff(const float* __restrict__ partS,
                                             const float* __restrict__ partQ,
                                             const float* __restrict__ gamma,
                                             const float* __restrict__ beta,
                                             float* __restrict__ aff_a,
                                             float* __restrict__ aff_b,
                                             const int* __restrict__ gstart,
                                             const int* __restrict__ gend,
                                             float* __restrict__ countsf, int N) {
  int t = threadIdx.x;
  if (t < NGRAPH) countsf[t] = fmaxf((float)(gend[t] - gstart[t]), 1.0f);
  if (t < FDIM) {
    float a = 0.f, b = 0.f;
    for (int bk = 0; bk < STATS_BLOCKS; bk++) {
      a += partS[bk * 128 + t];
      b += partQ[bk * 128 + t];
    }
    float invN = 1.0f / (float)N;
    float mu = a * invN;
    float var = b * invN - mu * mu;
    float inv = rsqrtf(var + 1e-5f);
    float ga = gamma[t] * inv;
    aff_a[t] = ga;
    aff_b[t] = beta[t] - mu * ga;
  }
}

// ---------- MEGA: gemm0 Hraw=(aff*x)@W (blocks < gemmBlocks, K-tiled 16KB LDS)
// ----------       + ELL edge ingest (remaining blocks) — the two overlap ----------
__global__ __launch_bounds__(256) void k_mega(const float* __restrict__ x,
                                              const float* __restrict__ aff_a,
                                              const float* __restrict__ aff_b,
                                              const float* __restrict__ W,
                                              __half* __restrict__ Hout, int gemmBlocks,
                                              const int* __restrict__ src,
                                              const int* __restrict__ dst,
                                              int* __restrict__ cursor,
                                              int* __restrict__ ell_src, int E, int N) {
  int t = threadIdx.x;
  if (blockIdx.x >= gemmBlocks) {
    int e = (blockIdx.x - gemmBlocks) * 256 + t;
    if (e < E) {
      int s = src[e], d = dst[e];
      if (s != d) {
        int p = atomicAdd(cursor + (size_t)d * CSTRIDE, 1);
        if (p < ELLCAP) ell_src[(size_t)d * ELLCAP + p] = s;
      }
    }
    return;  // edge blocks never reach the barriers below
  }
  __shared__ float sW[32 * 128];   // 16 KB K-tile of W
  __shared__ float sA[128];
  __shared__ float sB[128];
  if (t < 128) { sA[t] = aff_a[t]; sB[t] = aff_b[t]; }
  int tx = t & 31, ty = t >> 5;
  int nodeBase = blockIdx.x * 64 + ty * 8;
  int nidx[8];
#pragma unroll
  for (int i = 0; i < 8; i++) nidx[i] = min(nodeBase + i, N - 1);
  float acc[8][4];
#pragma unroll
  for (int i = 0; i < 8; i++) { acc[i][0] = acc[i][1] = acc[i][2] = acc[i][3] = 0.f; }
  for (int kk = 0; kk < 128; kk += 32) {
    __syncthreads();
#pragma unroll
    for (int i = 0; i < 4; i++) {
      int idx = t * 4 + i * 1024;
      *(float4*)(sW + idx) = *(const float4*)(W + kk * 128 + idx);
    }
    __syncthreads();
#pragma unroll 2
    for (int k2 = 0; k2 < 32; k2 += 4) {
      int k = kk + k2;
      float4 b0 = *(const float4*)(sW + (k2 + 0) * 128 + tx * 4);
      float4 b1 = *(const float4*)(sW + (k2 + 1) * 128 + tx * 4);
      float4 b2 = *(const float4*)(sW + (k2 + 2) * 128 + tx * 4);
      float4 b3 = *(const float4*)(sW + (k2 + 3) * 128 + tx * 4);
      float4 va = *(const float4*)(sA + k);
      float4 vb = *(const float4*)(sB + k);
#pragma unroll
      for (int i = 0; i < 8; i++) {
        float4 a = *(const float4*)(x + (size_t)nidx[i] * 128 + k);
        a.x = fmaf(a.x, va.x, vb.x);
        a.y = fmaf(a.y, va.y, vb.y);
        a.z = fmaf(a.z, va.z, vb.z);
        a.w = fmaf(a.w, va.w, vb.w);
        acc[i][0] = fmaf(a.w, b3.x, fmaf(a.z, b2.x, fmaf(a.y, b1.x, fmaf(a.x, b0.x, acc[i][0]))));
        acc[i][1] = fmaf(a.w, b3.y, fmaf(a.z, b2.y, fmaf(a.y, b1.y, fmaf(a.x, b0.y, acc[i][1]))));
        acc[i][2] = fmaf(a.w, b3.z, fmaf(a.z, b2.z, fmaf(a.y, b1.z, fmaf(a.x, b0.z, acc[i][2]))));
        acc[i][3] = fmaf(a.w, b3.w, fmaf(a.z, b2.w, fmaf(a.y, b1.w, fmaf(a.x, b0.w, acc[i][3]))));
      }
    }
  }
#pragma unroll
  for (int i = 0; i < 8; i++) {
    int node = nodeBase + i;
    if (node < N) {
      __half2 p0 = __floats2half2_rn(acc[i][0], acc[i][1]);
      __half2 p1 = __floats2half2_rn(acc[i][2], acc[i][3]);
      uint2 st;
      st.x = *(unsigned*)&p0;
      st.y = *(unsigned*)&p1;
      *(uint2*)(Hout + (size_t)node * 128 + tx * 4) = st;
    }
  }
}

// ---------- post: scale H by dinv (from cursor) + write deg/dinv arrays ----------
__global__ __launch_bounds__(256) void k_post(const int* __restrict__ cursor,
                                              int* __restrict__ deg,
                                              float* __restrict__ dinv,
                                              __half2* __restrict__ H,
                                              int nScaleBlocks, int N) {
  int t = threadIdx.x;
  if (blockIdx.x < nScaleBlocks) {
    int wv = t >> 6, l = t & 63;
    int row = blockIdx.x * 4 + wv;
    if (row >= N) return;
    float dv = rsqrtf(1.0f + (float)min(cursor[(size_t)row * CSTRIDE], ELLCAP));
    float2 f = __half22float2(H[(size_t)row * 64 + l]);
    H[(size_t)row * 64 + l] = __floats2half2_rn(f.x * dv, f.y * dv);
  } else {
    int i = (blockIdx.x - nScaleBlocks) * 256 + t;
    if (i < N) {
      int d = min(cursor[(size_t)i * CSTRIDE], ELLCAP);
      deg[i] = d;
      dinv[i] = rsqrtf(1.0f + (float)d);
    }
  }
}

// ---------- fused: ELL aggregate + squash + attention + graph scatter
// ----------        + MFMA epilogue: Hnext = (dn*X) @ W  (GEMM=1) ----------
// One wave per dst node; lane l owns features 2l,2l+1. ILP-4 padded edge loop.
// Epilogue: block's 8 nodes' dn*X staged in LDS (16-row zero-padded, pitch 136);
// wave w computes cols [16w,16w+16) of Hnext for the 8 nodes via 4 MFMAs.
// A-frag: sX[lane&15][ks*32+quad*8..+7]; B-frag: WT[col][...]; C/D row=quad*4+reg.
template <int GEMM>
__global__ __launch_bounds__(512) void k_agg_squash(const __half2* __restrict__ H,
                                                    _Float16* __restrict__ Hnext,
                                                    const _Float16* __restrict__ WT,
                                                    const int* __restrict__ deg,
                                                    const int* __restrict__ ell_src,
                                                    const float* __restrict__ bias,
                                                    const float* __restrict__ watt,
                                                    const int* __restrict__ batch,
                                                    const float* __restrict__ dinv,
                                                    float* __restrict__ wsum,
                                                    float* __restrict__ msum,
                                                    unsigned* __restrict__ maxenc, int N) {
  __shared__ float l_ws[128];
  __shared__ float l_ms[128];
  __shared__ unsigned l_mx[128];
  __shared__ _Float16 sX[16 * SXPITCH];   // rows 8..15 stay zero (MFMA pad)
  int t = threadIdx.x;
  if (t < 128) { l_ws[t] = 0.f; l_ms[t] = 0.f; l_mx[t] = 0u; }
  if (GEMM) {
    // zero pad rows 8..15 (8*136 = 1088 halfs)
    for (int i = t; i < 8 * SXPITCH; i += 512) sX[8 * SXPITCH + i] = (_Float16)0.f;
  }
  __syncthreads();

  int wv = t >> 6, l = t & 63;
  int node = blockIdx.x * AGG_NODES + wv;
  int g0 = batch[blockIdx.x * AGG_NODES];
  bool valid = node < N;
  float2 xv = make_float2(0.f, 0.f);
  float att = 0.f;
  float dn = 0.f;
  int g = g0;
  if (valid) {
    float2 h0 = __half22float2(H[(size_t)node * 64 + l]);
    float a0x = h0.x, a0y = h0.y;
    float a1x = 0.f, a1y = 0.f, a2x = 0.f, a2y = 0.f, a3x = 0.f, a3y = 0.f;
    size_t base = (size_t)node * ELLCAP;
    int cnt = deg[node];
    for (int j = 0; j < cnt; j += 4) {
      int4 ss = *(const int4*)(ell_src + base + j);   // broadcast 16B
      bool v1 = (j + 1 < cnt), v2 = (j + 2 < cnt), v3 = (j + 3 < cnt);
      int s0 = ss.x;
      int s1 = v1 ? ss.y : 0;
      int s2 = v2 ? ss.z : 0;
      int s3 = v3 ? ss.w : 0;
      float m1 = v1 ? 1.f : 0.f;
      float m2 = v2 ? 1.f : 0.f;
      float m3 = v3 ? 1.f : 0.f;
      float2 r0 = __half22float2(H[(size_t)s0 * 64 + l]);
      float2 r1 = __half22float2(H[(size_t)s1 * 64 + l]);
      float2 r2 = __half22float2(H[(size_t)s2 * 64 + l]);
      float2 r3 = __half22float2(H[(size_t)s3 * 64 + l]);
      a0x += r0.x;               a0y += r0.y;
      a1x = fmaf(m1, r1.x, a1x); a1y = fmaf(m1, r1.y, a1y);
      a2x = fmaf(m2, r2.x, a2x); a2y = fmaf(m2, r2.y, a2y);
      a3x = fmaf(m3, r3.x, a3x); a3y = fmaf(m3, r3.y, a3y);
    }
    dn = dinv[node];
    float2 bb = *(const float2*)(bias + 2 * l);
    float ax = fmaf(dn, (a0x + a1x) + (a2x + a3x), bb.x);
    float ay = fmaf(dn, (a0y + a1y) + (a2y + a3y), bb.y);
    float p = ax * ax + ay * ay;
#pragma unroll
    for (int m = 1; m < 64; m <<= 1) p += __shfl_xor(p, m);
    float factor = (p / (1.0f + p)) * rsqrtf(p + 1e-8f);
    xv = make_float2(ax * factor, ay * factor);
    float2 wa = *(const float2*)(watt + 2 * l);
    att = xv.x * wa.x + xv.y * wa.y;
#pragma unroll
    for (int m = 1; m < 64; m <<= 1) att += __shfl_xor(att, m);
    g = batch[node];
  }
  if (GEMM) {
    // stage dn*X into LDS (zeros for invalid nodes)
    __half2 sxv = __floats2half2_rn(xv.x * dn, xv.y * dn);
    *(__half2*)(sX + wv * SXPITCH + 2 * l) = sxv;
  }
  if (valid) {
    int fb = 2 * l;
    if (g == g0) {
      atomicAdd(&l_ws[fb + 0], att * xv.x);
      atomicAdd(&l_ws[fb + 1], att * xv.y);
      atomicAdd(&l_ms[fb + 0], xv.x);
      atomicAdd(&l_ms[fb + 1], xv.y);
      atomicMax(&l_mx[fb + 0], encf(xv.x));
      atomicMax(&l_mx[fb + 1], encf(xv.y));
    } else {  // rare: graph boundary inside block
      int base = g * 128 + fb;
      atomicAdd(wsum + base + 0, att * xv.x);
      atomicAdd(wsum + base + 1, att * xv.y);
      atomicAdd(msum + base + 0, xv.x);
      atomicAdd(msum + base + 1, xv.y);
      atomicMax(maxenc + base + 0, encf(xv.x));
      atomicMax(maxenc + base + 1, encf(xv.y));
    }
  }
  __syncthreads();
  if (t < 128) {
    int base = g0 * 128 + t;
    atomicAdd(wsum + base, l_ws[t]);
    atomicAdd(msum + base, l_ms[t]);
    unsigned u = l_mx[t];
    if (u) atomicMax(maxenc + base, u);
  }
  if (GEMM) {
    int r16 = l & 15, quad = l >> 4;
    int col = wv * 16 + r16;          // this wave's output column
    floatx4 acc = (floatx4){0.f, 0.f, 0.f, 0.f};
#pragma unroll
    for (int ks = 0; ks < 4; ks++) {
      half8 afrag = *(const half8*)(sX + r16 * SXPITCH + ks * 32 + quad * 8);
      half8 bfrag = *(const half8*)(WT + (size_t)col * 128 + ks * 32 + quad * 8);
      acc = __builtin_amdgcn_mfma_f32_16x16x32_f16(afrag, bfrag, acc, 0, 0, 0);
    }
#pragma unroll
    for (int j = 0; j < 4; j++) {
      int row = quad * 4 + j;          // node index within block (rows 8..15 are pad)
      int nnode = blockIdx.x * AGG_NODES + row;
      if (row < AGG_NODES && nnode < N)
        Hnext[(size_t)nnode * 128 + col] = (_Float16)acc[j];
    }
  }
}

// ---------- MLP head + log_softmax, one block per graph ----------
__global__ __launch_bounds__(128) void k_head(const float* __restrict__ wsum,
                                              const float* __restrict__ msum,
                                              const unsigned* __restrict__ maxenc,
                                              const float* __restrict__ countsf,
                                              const float* __restrict__ l1w,
                                              const float* __restrict__ l1b,
                                              const float* __restrict__ l2w,
                                              const float* __restrict__ l2b,
                                              float* __restrict__ out) {
  int g = blockIdx.x, t = threadIdx.x;
  __shared__ float rep[384];
  __shared__ float h1[128];
  __shared__ float lg[NCLS];
  float invc = 1.0f / countsf[g];
  rep[t] = wsum[g * 128 + t];
  rep[128 + t] = msum[g * 128 + t] * invc;
  rep[256 + t] = decf(maxenc[g * 128 + t]) +
                 decf(maxenc[NGRAPH * 128 + g * 128 + t]) +
                 decf(maxenc[2 * NGRAPH * 128 + g * 128 + t]);
  __syncthreads();
  float acc = l1b[t];
  for (int k = 0; k < 384; k++) acc = fmaf(rep[k], l1w[k * 128 + t], acc);
  h1[t] = fmaxf(acc, 0.f);
  __syncthreads();
  if (t < NCLS) {
    float a = l2b[t];
    for (int j = 0; j < 128; j++) a = fmaf(h1[j], l2w[j * NCLS + t], a);
    lg[t] = a;
  }
  __syncthreads();
  if (t < NCLS) {
    float m = lg[0];
    for (int c = 1; c < NCLS; c++) m = fmaxf(m, lg[c]);
    float s = 0.f;
    for (int c = 0; c < NCLS; c++) s += expf(lg[c] - m);
    out[g * NCLS + t] = lg[t] - m - logf(s);
  }
}

extern "C" void kernel_launch(void* const* d_in, const int* in_sizes, int n_in,
                              void* d_out, int out_size, void* d_ws, size_t ws_size,
                              hipStream_t stream) {
  const float* x      = (const float*)d_in[0];
  const int* edge     = (const int*)d_in[1];
  const int* batch    = (const int*)d_in[2];
  const float* gamma  = (const float*)d_in[3];
  const float* beta   = (const float*)d_in[4];
  const float* gcn_w  = (const float*)d_in[5];
  const float* gcn_b  = (const float*)d_in[6];
  const float* w_att  = (const float*)d_in[7];
  const float* l1w    = (const float*)d_in[8];
  const float* l1b    = (const float*)d_in[9];
  const float* l2w    = (const float*)d_in[10];
  const float* l2b    = (const float*)d_in[11];
  float* out          = (float*)d_out;

  const int N = in_sizes[0] / FDIM;   // 50000
  const int E = in_sizes[1] / 2;      // 640000
  const int* esrc = edge;
  const int* edst = edge + E;

  char* w = (char*)d_ws;
  size_t off = 0;
  auto alloc = [&](size_t bytes) {
    void* p = (void*)(w + off);
    off += (bytes + 1023) & ~(size_t)1023;
    return p;
  };
  __half* H0 = (__half*)alloc((size_t)N * FDIM * 2);
  __half* H1 = (__half*)alloc((size_t)N * FDIM * 2);
  // zero zone start
  size_t zoff = off;
  int* cursor      = (int*)alloc((size_t)N * CSTRIDE * 4);   // 1 counter per cache line
  int* gstart      = (int*)alloc(NGRAPH * 4);
  int* gend        = (int*)alloc(NGRAPH * 4);
  float* wsum      = (float*)alloc(NGRAPH * FDIM * 4);
  float* msum      = (float*)alloc(NGRAPH * FDIM * 4);
  unsigned* maxenc = (unsigned*)alloc((size_t)3 * NGRAPH * FDIM * 4);  // per-layer
  size_t zbytes = off - zoff;
  // non-zeroed
  float* partS    = (float*)alloc((size_t)STATS_BLOCKS * FDIM * 4);
  float* partQ    = (float*)alloc((size_t)STATS_BLOCKS * FDIM * 4);
  int* deg        = (int*)alloc((size_t)N * 4);
  float* dinv     = (float*)alloc((size_t)N * 4);
  float* countsf  = (float*)alloc(NGRAPH * 4);
  float* aff_a    = (float*)alloc(FDIM * 4);
  float* aff_b    = (float*)alloc(FDIM * 4);
  __half* W16T    = (__half*)alloc((size_t)2 * FDIM * FDIM * 2);  // W1^T,W2^T fp16
  int* ell_src    = (int*)alloc((size_t)N * ELLCAP * 4 + 1024);  // +slack for int4 overread
  (void)ws_size; (void)n_in; (void)out_size;

  hipMemsetAsync(w + zoff, 0, zbytes, stream);

  const int nbN = (N + 255) / 256;
  const int nbE = (E + 255) / 256;
  const int total4 = N * FDIM / 4;
  const int gemmBlocks = (N + 63) / 64;
  const int aggBlocks = (N + AGG_NODES - 1) / AGG_NODES;
  const int nScaleBlocks = (N + 3) / 4;
  const int nbW = (2 * FDIM * FDIM + 255) / 256;

  k_bn<<<STATS_BLOCKS + nbN + nbW, 256, 0, stream>>>(x, partS, partQ, total4, batch,
                                                     gstart, gend, gcn_w, W16T, nbN, N);
  k_aff<<<1, 256, 0, stream>>>(partS, partQ, gamma, beta, aff_a, aff_b,
                               gstart, gend, countsf, N);
  k_mega<<<gemmBlocks + nbE, 256, 0, stream>>>(x, aff_a, aff_b, gcn_w, H0, gemmBlocks,
                                               esrc, edst, cursor, ell_src, E, N);
  k_post<<<nScaleBlocks + nbN, 256, 0, stream>>>(cursor, deg, dinv, (__half2*)H0,
                                                 nScaleBlocks, N);

  // layer 0: read H0, MFMA-epilogue with W1^T -> H1
  k_agg_squash<1><<<aggBlocks, 512, 0, stream>>>((const __half2*)H0, (_Float16*)H1,
                                                 (const _Float16*)W16T,
                                                 deg, ell_src, gcn_b, w_att, batch, dinv,
                                                 wsum, msum, maxenc, N);
  // layer 1: read H1, MFMA-epilogue with W2^T -> H0
  k_agg_squash<1><<<aggBlocks, 512, 0, stream>>>((const __half2*)H1, (_Float16*)H0,
                                                 (const _Float16*)(W16T + FDIM * FDIM),
                                                 deg, ell_src, gcn_b + FDIM, w_att + FDIM,
                                                 batch, dinv, wsum, msum,
                                                 maxenc + (size_t)NGRAPH * FDIM, N);
  // layer 2: read H0, no epilogue
  k_agg_squash<0><<<aggBlocks, 512, 0, stream>>>((const __half2*)H0, nullptr, nullptr,
                                                 deg, ell_src, gcn_b + 2 * FDIM,
                                                 w_att + 2 * FDIM, batch, dinv,
                                                 wsum, msum,
                                                 maxenc + (size_t)2 * NGRAPH * FDIM, N);
  k_head<<<NGRAPH, 128, 0, stream>>>(wsum, msum, maxenc, countsf, l1w, l1b, l2w, l2b, out);
}